// Round 1
// baseline (516.762 us; speedup 1.0000x reference)
//
#include <hip/hip_runtime.h>
#include <stddef.h>

#define N_NODES 10000
#define N_EDGES 160000
#define DIM     512

// ---------------- graph preprocessing ----------------

__global__ void zero_int_kernel(int* __restrict__ p, int n) {
    int i = blockIdx.x * blockDim.x + threadIdx.x;
    if (i < n) p[i] = 0;
}

__global__ void count_deg_kernel(const int* __restrict__ ei, int* __restrict__ deg, int E) {
    int e = blockIdx.x * blockDim.x + threadIdx.x;
    if (e < E) atomicAdd(&deg[ei[E + e]], 1);
}

__global__ void dis_kernel(const int* __restrict__ deg, float* __restrict__ dis, int n) {
    int i = blockIdx.x * blockDim.x + threadIdx.x;
    if (i < n) dis[i] = rsqrtf((float)(deg[i] + 1));  // +1 self-loop, always >= 1
}

// single-block inclusive scan of deg -> row_off (row_off[0]=0, row_off[i+1]=sum deg[0..i])
__global__ void scan_kernel(const int* __restrict__ deg, int* __restrict__ row_off, int n) {
    __shared__ int sm[1024];
    __shared__ int carry_s;
    if (threadIdx.x == 0) carry_s = 0;
    __syncthreads();
    for (int base = 0; base < n; base += 1024) {
        int i = base + (int)threadIdx.x;
        int v = (i < n) ? deg[i] : 0;
        sm[threadIdx.x] = v;
        __syncthreads();
        for (int off = 1; off < 1024; off <<= 1) {
            int t = (threadIdx.x >= (unsigned)off) ? sm[threadIdx.x - off] : 0;
            __syncthreads();
            sm[threadIdx.x] += t;
            __syncthreads();
        }
        int carry = carry_s;
        if (i < n) row_off[i + 1] = sm[threadIdx.x] + carry;
        __syncthreads();
        if (threadIdx.x == 1023) carry_s = carry + sm[1023];
        __syncthreads();
    }
    if (threadIdx.x == 0) row_off[0] = 0;
}

__global__ void scatter_kernel(const int* __restrict__ ei, const float* __restrict__ dis,
                               const int* __restrict__ row_off, int* __restrict__ cursor,
                               int* __restrict__ csr_src, float* __restrict__ csr_norm, int E) {
    int e = blockIdx.x * blockDim.x + threadIdx.x;
    if (e >= E) return;
    int s = ei[e];
    int d = ei[E + e];
    int slot = row_off[d] + atomicAdd(&cursor[d], 1);
    csr_src[slot]  = s;
    csr_norm[slot] = dis[s] * dis[d];
}

// ---------------- f32 GEMM: C[M,N] = op(A[M,K]) @ B[K,N] + bias, optional relu ----------------
// 64x64 tile, BK=16, 256 threads, 4x4 per thread.

template<bool RELU_IN, bool RELU_OUT>
__global__ __launch_bounds__(256) void sgemm_kernel(const float* __restrict__ A,
                                                    const float* __restrict__ B,
                                                    const float* __restrict__ bias,
                                                    float* __restrict__ C,
                                                    int M, int K, int N) {
    __shared__ float As[16][68];  // [k][row], padded: 68*4=272B row stride (16B aligned, conflict-light)
    __shared__ float Bs[16][64];  // [k][col]

    const int tid = threadIdx.x;
    const int tx = tid & 15;          // col group
    const int ty = tid >> 4;          // row group
    const int row0 = blockIdx.y * 64 + ty * 4;
    const int col0 = blockIdx.x * 64 + tx * 4;

    // A-load mapping: 64 rows x 16 k, float4 per thread
    const int lrow = tid >> 2;
    const int lk4  = (tid & 3) * 4;
    const int arow = blockIdx.y * 64 + lrow;
    // B-load mapping: 16 k-rows x 64 cols, float4 per thread
    const int lkb   = tid >> 4;
    const int lcol4 = (tid & 15) * 4;
    const int bcol  = blockIdx.x * 64 + lcol4;

    float acc[4][4] = {};

    for (int k0 = 0; k0 < K; k0 += 16) {
        float4 av = make_float4(0.f, 0.f, 0.f, 0.f);
        if (arow < M) av = *(const float4*)(A + (size_t)arow * K + k0 + lk4);
        if (RELU_IN) {
            av.x = fmaxf(av.x, 0.f); av.y = fmaxf(av.y, 0.f);
            av.z = fmaxf(av.z, 0.f); av.w = fmaxf(av.w, 0.f);
        }
        As[lk4 + 0][lrow] = av.x;
        As[lk4 + 1][lrow] = av.y;
        As[lk4 + 2][lrow] = av.z;
        As[lk4 + 3][lrow] = av.w;

        float4 bv = *(const float4*)(B + (size_t)(k0 + lkb) * N + bcol);
        *(float4*)&Bs[lkb][lcol4] = bv;

        __syncthreads();

#pragma unroll
        for (int kk = 0; kk < 16; ++kk) {
            float4 a = *(const float4*)&As[kk][ty * 4];
            float4 b = *(const float4*)&Bs[kk][tx * 4];
            acc[0][0] += a.x * b.x; acc[0][1] += a.x * b.y; acc[0][2] += a.x * b.z; acc[0][3] += a.x * b.w;
            acc[1][0] += a.y * b.x; acc[1][1] += a.y * b.y; acc[1][2] += a.y * b.z; acc[1][3] += a.y * b.w;
            acc[2][0] += a.z * b.x; acc[2][1] += a.z * b.y; acc[2][2] += a.z * b.z; acc[2][3] += a.z * b.w;
            acc[3][0] += a.w * b.x; acc[3][1] += a.w * b.y; acc[3][2] += a.w * b.z; acc[3][3] += a.w * b.w;
        }
        __syncthreads();
    }

    const float4 bi = *(const float4*)(bias + col0);
#pragma unroll
    for (int i = 0; i < 4; ++i) {
        int row = row0 + i;
        if (row < M) {
            float4 c;
            c.x = acc[i][0] + bi.x;
            c.y = acc[i][1] + bi.y;
            c.z = acc[i][2] + bi.z;
            c.w = acc[i][3] + bi.w;
            if (RELU_OUT) {
                c.x = fmaxf(c.x, 0.f); c.y = fmaxf(c.y, 0.f);
                c.z = fmaxf(c.z, 0.f); c.w = fmaxf(c.w, 0.f);
            }
            *(float4*)(C + (size_t)row * N + col0) = c;
        }
    }
}

// ---------------- aggregation: out[i] = sum_{e: dst=i} H[src_e]*norm_e + H[i]*dis[i]^2 ----------------

__global__ __launch_bounds__(256) void aggregate_kernel(const float* __restrict__ H,
                                                        const float* __restrict__ dis,
                                                        const int* __restrict__ row_off,
                                                        const int* __restrict__ csr_src,
                                                        const float* __restrict__ csr_norm,
                                                        float* __restrict__ out) {
    const int node = blockIdx.x;
    const int f = threadIdx.x;      // features f and f+256
    const int start = row_off[node];
    const int end   = row_off[node + 1];
    const float dn = dis[node];
    const float sw = dn * dn;

    const float* hn = H + (size_t)node * DIM;
    float a0 = hn[f] * sw;
    float a1 = hn[f + 256] * sw;

    for (int e = start; e < end; ++e) {
        int s   = csr_src[e];
        float w = csr_norm[e];
        const float* hs = H + (size_t)s * DIM;
        a0 += hs[f] * w;
        a1 += hs[f + 256] * w;
    }
    out[(size_t)node * DIM + f]       = a0;
    out[(size_t)node * DIM + 256 + f] = a1;
}

// ---------------- launch ----------------

extern "C" void kernel_launch(void* const* d_in, const int* in_sizes, int n_in,
                              void* d_out, int out_size, void* d_ws, size_t ws_size,
                              hipStream_t stream) {
    const float* x   = (const float*)d_in[0];
    const int*   ei  = (const int*)d_in[1];     // [2, E] int32: [0..E)=src, [E..2E)=dst
    const float* W1  = (const float*)d_in[2];
    const float* b1  = (const float*)d_in[3];
    const float* W2  = (const float*)d_in[4];
    const float* b2  = (const float*)d_in[5];
    const float* Wp1 = (const float*)d_in[6];
    const float* bp1 = (const float*)d_in[7];
    const float* Wp2 = (const float*)d_in[8];
    const float* bp2 = (const float*)d_in[9];

    float* out  = (float*)d_out;                          // [N, DIM]
    float* z    = out + (size_t)N_NODES * DIM;            // [N, DIM]
    float* proj = z   + (size_t)N_NODES * DIM;            // [N, DIM]

    char* ws = (char*)d_ws;
    size_t off = 0;
    auto walloc = [&](size_t bytes) -> void* {
        void* p = ws + off;
        off = (off + bytes + 255) & ~(size_t)255;
        return p;
    };
    float* H        = (float*)walloc((size_t)N_NODES * DIM * sizeof(float));  // 20.48 MB, reused
    int*   deg      = (int*)  walloc(N_NODES * sizeof(int));
    int*   cursor   = (int*)  walloc(N_NODES * sizeof(int));
    int*   row_off  = (int*)  walloc((N_NODES + 1) * sizeof(int));
    float* dis      = (float*)walloc(N_NODES * sizeof(float));
    int*   csr_src  = (int*)  walloc(N_EDGES * sizeof(int));
    float* csr_norm = (float*)walloc(N_EDGES * sizeof(float));

    const dim3 blk(256);
    const dim3 gN((N_NODES + 255) / 256);
    const dim3 gE((N_EDGES + 255) / 256);

    zero_int_kernel<<<gN, blk, 0, stream>>>(deg, N_NODES);
    zero_int_kernel<<<gN, blk, 0, stream>>>(cursor, N_NODES);
    count_deg_kernel<<<gE, blk, 0, stream>>>(ei, deg, N_EDGES);
    dis_kernel<<<gN, blk, 0, stream>>>(deg, dis, N_NODES);
    scan_kernel<<<1, 1024, 0, stream>>>(deg, row_off, N_NODES);
    scatter_kernel<<<gE, blk, 0, stream>>>(ei, dis, row_off, cursor, csr_src, csr_norm, N_EDGES);

    const dim3 gemm_grid(DIM / 64, (N_NODES + 63) / 64);

    // z = aggregate(x @ W1 + b1)
    sgemm_kernel<false, false><<<gemm_grid, blk, 0, stream>>>(x, W1, b1, H, N_NODES, DIM, DIM);
    aggregate_kernel<<<N_NODES, blk, 0, stream>>>(H, dis, row_off, csr_src, csr_norm, z);

    // out = aggregate(relu(z) @ W2 + b2)
    sgemm_kernel<true, false><<<gemm_grid, blk, 0, stream>>>(z, W2, b2, H, N_NODES, DIM, DIM);
    aggregate_kernel<<<N_NODES, blk, 0, stream>>>(H, dis, row_off, csr_src, csr_norm, out);

    // proj = relu(z @ Wp1 + bp1) @ Wp2 + bp2
    sgemm_kernel<false, true><<<gemm_grid, blk, 0, stream>>>(z, Wp1, bp1, H, N_NODES, DIM, DIM);
    sgemm_kernel<false, false><<<gemm_grid, blk, 0, stream>>>(H, Wp2, bp2, proj, N_NODES, DIM, DIM);
}

// Round 2
// 444.719 us; speedup vs baseline: 1.1620x; 1.1620x over previous
//
#include <hip/hip_runtime.h>
#include <stddef.h>

#define N_NODES 10000
#define N_EDGES 160000
#define DIM     512

typedef short bf16x8 __attribute__((ext_vector_type(8)));
typedef float f32x4  __attribute__((ext_vector_type(4)));

__device__ inline unsigned short bf16_rne(float f) {
    unsigned u = __builtin_bit_cast(unsigned, f);
    u += 0x7FFF + ((u >> 16) & 1);
    return (unsigned short)(u >> 16);
}
__device__ inline float bf16_to_f32(unsigned short h) {
    unsigned u = ((unsigned)h) << 16;
    return __builtin_bit_cast(float, u);
}

// ---------------- graph preprocessing ----------------

__global__ void zero_int_kernel(int* __restrict__ p, int n) {
    int i = blockIdx.x * blockDim.x + threadIdx.x;
    if (i < n) p[i] = 0;
}

__global__ void count_deg_kernel(const int* __restrict__ ei, int* __restrict__ deg, int E) {
    int e = blockIdx.x * blockDim.x + threadIdx.x;
    if (e < E) atomicAdd(&deg[ei[E + e]], 1);
}

__global__ void dis_kernel(const int* __restrict__ deg, float* __restrict__ dis, int n) {
    int i = blockIdx.x * blockDim.x + threadIdx.x;
    if (i < n) dis[i] = rsqrtf((float)(deg[i] + 1));  // +1 self-loop, always >= 1
}

__global__ void scan_kernel(const int* __restrict__ deg, int* __restrict__ row_off, int n) {
    __shared__ int sm[1024];
    __shared__ int carry_s;
    if (threadIdx.x == 0) carry_s = 0;
    __syncthreads();
    for (int base = 0; base < n; base += 1024) {
        int i = base + (int)threadIdx.x;
        int v = (i < n) ? deg[i] : 0;
        sm[threadIdx.x] = v;
        __syncthreads();
        for (int off = 1; off < 1024; off <<= 1) {
            int t = (threadIdx.x >= (unsigned)off) ? sm[threadIdx.x - off] : 0;
            __syncthreads();
            sm[threadIdx.x] += t;
            __syncthreads();
        }
        int carry = carry_s;
        if (i < n) row_off[i + 1] = sm[threadIdx.x] + carry;
        __syncthreads();
        if (threadIdx.x == 1023) carry_s = carry + sm[1023];
        __syncthreads();
    }
    if (threadIdx.x == 0) row_off[0] = 0;
}

__global__ void scatter_kernel(const int* __restrict__ ei, const float* __restrict__ dis,
                               const int* __restrict__ row_off, int* __restrict__ cursor,
                               int* __restrict__ csr_src, float* __restrict__ csr_norm, int E) {
    int e = blockIdx.x * blockDim.x + threadIdx.x;
    if (e >= E) return;
    int s = ei[e];
    int d = ei[E + e];
    int slot = row_off[d] + atomicAdd(&cursor[d], 1);
    csr_src[slot]  = s;
    csr_norm[slot] = dis[s] * dis[d];
}

// ---------------- weight pre-pack: W[512][512] f32 -> packed transposed bf16 hi/lo ----------------
// Layout: [nb=4][kb=16][arr=2(hi,lo)][col=128][k=32] bf16 -> per (nb,kb) tile is 8192
// contiguous elements (16 KB), staged with perfectly coalesced 16B/lane loads.

__global__ __launch_bounds__(256) void pack_weight_kernel(const float* __restrict__ W,
                                                          unsigned short* __restrict__ WT) {
    int id = blockIdx.x * 256 + threadIdx.x;   // 32768 threads
    int n  = id & 511;                         // output col, coalesced reads over n
    int kc = id >> 9;                          // k-chunk of 8, 0..63
    int nb = n >> 7, col = n & 127;
    int kb = kc >> 2, kq = kc & 3;
    unsigned short hi[8], lo[8];
#pragma unroll
    for (int j = 0; j < 8; ++j) {
        float v = W[(size_t)(kc * 8 + j) * 512 + n];
        unsigned short h = bf16_rne(v);
        hi[j] = h;
        lo[j] = bf16_rne(v - bf16_to_f32(h));
    }
    size_t base = ((((size_t)nb * 16 + kb) * 2 + 0) * 128 + col) * 32 + kq * 8;
    *(int4*)(WT + base)            = *(const int4*)hi;
    *(int4*)(WT + base + 128 * 32) = *(const int4*)lo;   // arr=1 plane is +128*32 elements
}

// ---------------- bf16-split MFMA GEMM: C[M,512] = op(A[M,512]) @ W + bias ----------------
// 128x128 tile, BK=32, 256 threads = 4 waves (2x2), wave computes 64x64 via 4x4 frags
// of v_mfma_f32_16x16x32_bf16, 3 products (hi*hi, hi*lo, lo*hi).

template<bool RELU_IN, bool RELU_OUT>
__global__ __launch_bounds__(256, 2) void mfma_gemm_kernel(
    const float* __restrict__ A,
    const unsigned short* __restrict__ WT,
    const float* __restrict__ bias,
    float* __restrict__ C,
    int M)
{
    __shared__ short As[2][128][40];   // [hi/lo][row][k], 80B row stride (<=2-way bank alias)
    __shared__ short Bs[2][128][40];   // [hi/lo][col][k]

    const int tid = threadIdx.x;
    const int row_base = blockIdx.y * 128;
    const int col_base = blockIdx.x * 128;

    const int wid  = tid >> 6;
    const int lane = tid & 63;
    const int wr = (wid >> 1) * 64;
    const int wc = (wid & 1) * 64;
    const int l15 = lane & 15;
    const int kg  = lane >> 4;

    // A staging: 8 lanes per row, float4 each; 4 iterations cover 128 rows x 32 k
    const int arow = tid >> 3;
    const int ak   = (tid & 7) * 4;

    f32x4 acc[4][4];
#pragma unroll
    for (int i = 0; i < 4; ++i)
#pragma unroll
        for (int j = 0; j < 4; ++j) acc[i][j] = (f32x4){0.f, 0.f, 0.f, 0.f};

    const unsigned short* WTb = WT + (size_t)blockIdx.x * 16 * 8192;

    for (int kt = 0; kt < 16; ++kt) {
        const int k0 = kt * 32;

        // issue global loads (overlap previous compute)
        float4 av[4];
#pragma unroll
        for (int it = 0; it < 4; ++it) {
            int grow = row_base + arow + it * 32;
            float4 v = make_float4(0.f, 0.f, 0.f, 0.f);
            if (grow < M) v = *(const float4*)(A + (size_t)grow * 512 + k0 + ak);
            if (RELU_IN) {
                v.x = fmaxf(v.x, 0.f); v.y = fmaxf(v.y, 0.f);
                v.z = fmaxf(v.z, 0.f); v.w = fmaxf(v.w, 0.f);
            }
            av[it] = v;
        }
        int4 bq[4];
        const unsigned short* WTt = WTb + (size_t)kt * 8192;
#pragma unroll
        for (int it = 0; it < 4; ++it)
            bq[it] = *(const int4*)(WTt + (size_t)(it * 256 + tid) * 8);

        __syncthreads();   // previous compute done reading LDS

#pragma unroll
        for (int it = 0; it < 4; ++it) {
            int r = arow + it * 32;
            float4 v = av[it];
            unsigned short h0 = bf16_rne(v.x), h1 = bf16_rne(v.y),
                           h2 = bf16_rne(v.z), h3 = bf16_rne(v.w);
            short4 hi = make_short4((short)h0, (short)h1, (short)h2, (short)h3);
            short4 lo = make_short4((short)bf16_rne(v.x - bf16_to_f32(h0)),
                                    (short)bf16_rne(v.y - bf16_to_f32(h1)),
                                    (short)bf16_rne(v.z - bf16_to_f32(h2)),
                                    (short)bf16_rne(v.w - bf16_to_f32(h3)));
            *(short4*)&As[0][r][ak] = hi;
            *(short4*)&As[1][r][ak] = lo;
        }
#pragma unroll
        for (int it = 0; it < 4; ++it) {
            int c   = it * 256 + tid;      // 0..1023
            int arr = c >> 9;
            int cc  = c & 511;
            int col = cc >> 2;
            int kq  = cc & 3;
            *(int4*)&Bs[arr][col][kq * 8] = bq[it];
        }

        __syncthreads();   // LDS tiles ready

        bf16x8 af[4][2], bf[4][2];
#pragma unroll
        for (int m = 0; m < 4; ++m) {
            int r = wr + m * 16 + l15;
#pragma unroll
            for (int s = 0; s < 2; ++s)
                af[m][s] = *(const bf16x8*)&As[s][r][kg * 8];
        }
#pragma unroll
        for (int n = 0; n < 4; ++n) {
            int cI = wc + n * 16 + l15;
#pragma unroll
            for (int s = 0; s < 2; ++s)
                bf[n][s] = *(const bf16x8*)&Bs[s][cI][kg * 8];
        }
#pragma unroll
        for (int m = 0; m < 4; ++m)
#pragma unroll
            for (int n = 0; n < 4; ++n) {
                acc[m][n] = __builtin_amdgcn_mfma_f32_16x16x32_bf16(af[m][0], bf[n][0], acc[m][n], 0, 0, 0);
                acc[m][n] = __builtin_amdgcn_mfma_f32_16x16x32_bf16(af[m][0], bf[n][1], acc[m][n], 0, 0, 0);
                acc[m][n] = __builtin_amdgcn_mfma_f32_16x16x32_bf16(af[m][1], bf[n][0], acc[m][n], 0, 0, 0);
            }
    }

    // epilogue: C/D layout col=lane&15, row=(lane>>4)*4+reg
#pragma unroll
    for (int n = 0; n < 4; ++n) {
        int col = col_base + wc + n * 16 + l15;
        float bv = bias[col];
#pragma unroll
        for (int m = 0; m < 4; ++m) {
            int r0 = row_base + wr + m * 16 + kg * 4;
#pragma unroll
            for (int j = 0; j < 4; ++j) {
                int row = r0 + j;
                if (row < M) {
                    float v = acc[m][n][j] + bv;
                    if (RELU_OUT) v = fmaxf(v, 0.f);
                    C[(size_t)row * 512 + col] = v;
                }
            }
        }
    }
}

// ---------------- aggregation: out[i] = sum_{e: dst=i} H[src_e]*norm_e + H[i]*dis[i]^2 ----------------

__global__ __launch_bounds__(256) void aggregate_kernel(const float* __restrict__ H,
                                                        const float* __restrict__ dis,
                                                        const int* __restrict__ row_off,
                                                        const int* __restrict__ csr_src,
                                                        const float* __restrict__ csr_norm,
                                                        float* __restrict__ out) {
    const int node = blockIdx.x;
    const int f = threadIdx.x;
    const int start = row_off[node];
    const int end   = row_off[node + 1];
    const float dn = dis[node];
    const float sw = dn * dn;

    const float* hn = H + (size_t)node * DIM;
    float a0 = hn[f] * sw;
    float a1 = hn[f + 256] * sw;

    for (int e = start; e < end; ++e) {
        int s   = csr_src[e];
        float w = csr_norm[e];
        const float* hs = H + (size_t)s * DIM;
        a0 += hs[f] * w;
        a1 += hs[f + 256] * w;
    }
    out[(size_t)node * DIM + f]       = a0;
    out[(size_t)node * DIM + 256 + f] = a1;
}

// ---------------- launch ----------------

extern "C" void kernel_launch(void* const* d_in, const int* in_sizes, int n_in,
                              void* d_out, int out_size, void* d_ws, size_t ws_size,
                              hipStream_t stream) {
    const float* x   = (const float*)d_in[0];
    const int*   ei  = (const int*)d_in[1];
    const float* W1  = (const float*)d_in[2];
    const float* b1  = (const float*)d_in[3];
    const float* W2  = (const float*)d_in[4];
    const float* b2  = (const float*)d_in[5];
    const float* Wp1 = (const float*)d_in[6];
    const float* bp1 = (const float*)d_in[7];
    const float* Wp2 = (const float*)d_in[8];
    const float* bp2 = (const float*)d_in[9];

    float* out  = (float*)d_out;
    float* z    = out + (size_t)N_NODES * DIM;
    float* proj = z   + (size_t)N_NODES * DIM;

    char* ws = (char*)d_ws;
    size_t off = 0;
    auto walloc = [&](size_t bytes) -> void* {
        void* p = ws + off;
        off = (off + bytes + 255) & ~(size_t)255;
        return p;
    };
    float* H   = (float*)walloc((size_t)N_NODES * DIM * sizeof(float));   // 20.48 MB
    unsigned short* WT1  = (unsigned short*)walloc((size_t)512 * 512 * 2 * sizeof(unsigned short));
    unsigned short* WT2  = (unsigned short*)walloc((size_t)512 * 512 * 2 * sizeof(unsigned short));
    unsigned short* WTp1 = (unsigned short*)walloc((size_t)512 * 512 * 2 * sizeof(unsigned short));
    unsigned short* WTp2 = (unsigned short*)walloc((size_t)512 * 512 * 2 * sizeof(unsigned short));
    int*   deg      = (int*)  walloc(N_NODES * sizeof(int));
    int*   cursor   = (int*)  walloc(N_NODES * sizeof(int));
    int*   row_off  = (int*)  walloc((N_NODES + 1) * sizeof(int));
    float* dis      = (float*)walloc(N_NODES * sizeof(float));
    int*   csr_src  = (int*)  walloc(N_EDGES * sizeof(int));
    float* csr_norm = (float*)walloc(N_EDGES * sizeof(float));

    const dim3 blk(256);
    const dim3 gN((N_NODES + 255) / 256);
    const dim3 gE((N_EDGES + 255) / 256);

    // weight packing (independent of graph prep)
    pack_weight_kernel<<<128, blk, 0, stream>>>(W1,  WT1);
    pack_weight_kernel<<<128, blk, 0, stream>>>(W2,  WT2);
    pack_weight_kernel<<<128, blk, 0, stream>>>(Wp1, WTp1);
    pack_weight_kernel<<<128, blk, 0, stream>>>(Wp2, WTp2);

    zero_int_kernel<<<gN, blk, 0, stream>>>(deg, N_NODES);
    zero_int_kernel<<<gN, blk, 0, stream>>>(cursor, N_NODES);
    count_deg_kernel<<<gE, blk, 0, stream>>>(ei, deg, N_EDGES);
    dis_kernel<<<gN, blk, 0, stream>>>(deg, dis, N_NODES);
    scan_kernel<<<1, 1024, 0, stream>>>(deg, row_off, N_NODES);
    scatter_kernel<<<gE, blk, 0, stream>>>(ei, dis, row_off, cursor, csr_src, csr_norm, N_EDGES);

    const dim3 gemm_grid(DIM / 128, (N_NODES + 127) / 128);

    // z = aggregate(x @ W1 + b1)
    mfma_gemm_kernel<false, false><<<gemm_grid, blk, 0, stream>>>(x, WT1, b1, H, N_NODES);
    aggregate_kernel<<<N_NODES, blk, 0, stream>>>(H, dis, row_off, csr_src, csr_norm, z);

    // out = aggregate(relu(z) @ W2 + b2)
    mfma_gemm_kernel<true, false><<<gemm_grid, blk, 0, stream>>>(z, WT2, b2, H, N_NODES);
    aggregate_kernel<<<N_NODES, blk, 0, stream>>>(H, dis, row_off, csr_src, csr_norm, out);

    // proj = relu(z @ Wp1 + bp1) @ Wp2 + bp2
    mfma_gemm_kernel<false, true><<<gemm_grid, blk, 0, stream>>>(z, WTp1, bp1, H, N_NODES);
    mfma_gemm_kernel<false, false><<<gemm_grid, blk, 0, stream>>>(H, WTp2, bp2, proj, N_NODES);
}

// Round 3
// 325.238 us; speedup vs baseline: 1.5889x; 1.3674x over previous
//
#include <hip/hip_runtime.h>
#include <stddef.h>

#define N_NODES 10000
#define N_EDGES 160000
#define DIM     512
#define RBLKS   157   // ceil(10000/64)

typedef short bf16x8 __attribute__((ext_vector_type(8)));
typedef float f32x4  __attribute__((ext_vector_type(4)));

__device__ inline unsigned short bf16_rne(float f) {
    unsigned u = __builtin_bit_cast(unsigned, f);
    u += 0x7FFF + ((u >> 16) & 1);
    return (unsigned short)(u >> 16);
}
__device__ inline float bf16_to_f32(unsigned short h) {
    unsigned u = ((unsigned)h) << 16;
    return __builtin_bit_cast(float, u);
}

__device__ inline void gld_lds16(const void* g, void* lds) {
    __builtin_amdgcn_global_load_lds(
        (const __attribute__((address_space(1))) void*)g,
        (__attribute__((address_space(3))) void*)lds, 16, 0, 0);
}

// ---------------- graph preprocessing (unchanged, verified) ----------------

__global__ void zero_int_kernel(int* __restrict__ p, int n) {
    int i = blockIdx.x * blockDim.x + threadIdx.x;
    if (i < n) p[i] = 0;
}

__global__ void count_deg_kernel(const int* __restrict__ ei, int* __restrict__ deg, int E) {
    int e = blockIdx.x * blockDim.x + threadIdx.x;
    if (e < E) atomicAdd(&deg[ei[E + e]], 1);
}

__global__ void dis_kernel(const int* __restrict__ deg, float* __restrict__ dis, int n) {
    int i = blockIdx.x * blockDim.x + threadIdx.x;
    if (i < n) dis[i] = rsqrtf((float)(deg[i] + 1));
}

__global__ void scan_kernel(const int* __restrict__ deg, int* __restrict__ row_off, int n) {
    __shared__ int sm[1024];
    __shared__ int carry_s;
    if (threadIdx.x == 0) carry_s = 0;
    __syncthreads();
    for (int base = 0; base < n; base += 1024) {
        int i = base + (int)threadIdx.x;
        int v = (i < n) ? deg[i] : 0;
        sm[threadIdx.x] = v;
        __syncthreads();
        for (int off = 1; off < 1024; off <<= 1) {
            int t = (threadIdx.x >= (unsigned)off) ? sm[threadIdx.x - off] : 0;
            __syncthreads();
            sm[threadIdx.x] += t;
            __syncthreads();
        }
        int carry = carry_s;
        if (i < n) row_off[i + 1] = sm[threadIdx.x] + carry;
        __syncthreads();
        if (threadIdx.x == 1023) carry_s = carry + sm[1023];
        __syncthreads();
    }
    if (threadIdx.x == 0) row_off[0] = 0;
}

__global__ void scatter_kernel(const int* __restrict__ ei, const float* __restrict__ dis,
                               const int* __restrict__ row_off, int* __restrict__ cursor,
                               int* __restrict__ csr_src, float* __restrict__ csr_norm, int E) {
    int e = blockIdx.x * blockDim.x + threadIdx.x;
    if (e >= E) return;
    int s = ei[e];
    int d = ei[E + e];
    int slot = row_off[d] + atomicAdd(&cursor[d], 1);
    csr_src[slot]  = s;
    csr_norm[slot] = dis[s] * dis[d];
}

// ---------------- packing ----------------
// Tile layout (shorts): [blk][kt 16][arr 2(hi/lo)][idx 64][k 32], tile = 4096 shorts.
// XOR swizzle baked in: k-group slot kq stored at (kq ^ ((idx>>1)&3)).

__global__ __launch_bounds__(256) void pack_weight_kernel(const float* __restrict__ W,
                                                          short* __restrict__ WT) {
    int id = blockIdx.x * 256 + threadIdx.x;   // 32768
    int n  = id & 511;                         // coalesced over n
    int kc = id >> 9;                          // k-chunk of 8, 0..63
    int colblk = n >> 6, col = n & 63;
    int kt = kc >> 2, kq = kc & 3;
    short hi[8], lo[8];
#pragma unroll
    for (int j = 0; j < 8; ++j) {
        float v = W[(size_t)(kc * 8 + j) * 512 + n];
        unsigned short h = bf16_rne(v);
        hi[j] = (short)h;
        lo[j] = (short)bf16_rne(v - bf16_to_f32(h));
    }
    size_t base = (size_t)(colblk * 16 + kt) * 4096 + col * 32 + ((kq ^ ((col >> 1) & 3)) << 3);
    *(int4*)(WT + base)        = *(const int4*)hi;
    *(int4*)(WT + base + 2048) = *(const int4*)lo;
}

// pack A[M,512] f32 -> P0 (plain), and if DUAL also P1 (relu'd)
template<bool DUAL>
__global__ __launch_bounds__(256) void pack_a_kernel(const float* __restrict__ A,
                                                     short* __restrict__ P0,
                                                     short* __restrict__ P1, int M) {
    const int kt = blockIdx.x;         // 0..15
    const int rb = blockIdx.y;         // 0..RBLKS-1
    const int t  = threadIdx.x;
    const int r  = t >> 2;             // 0..63
    const int kq = t & 3;
    const int row = rb * 64 + r;
    float v[8] = {};
    if (row < M) {
        float4 a = *(const float4*)(A + (size_t)row * 512 + kt * 32 + kq * 8);
        float4 b = *(const float4*)(A + (size_t)row * 512 + kt * 32 + kq * 8 + 4);
        v[0]=a.x; v[1]=a.y; v[2]=a.z; v[3]=a.w; v[4]=b.x; v[5]=b.y; v[6]=b.z; v[7]=b.w;
    }
    size_t base = (size_t)(rb * 16 + kt) * 4096 + r * 32 + ((kq ^ ((r >> 1) & 3)) << 3);
    short hi[8], lo[8];
#pragma unroll
    for (int j = 0; j < 8; ++j) {
        unsigned short h = bf16_rne(v[j]);
        hi[j] = (short)h;
        lo[j] = (short)bf16_rne(v[j] - bf16_to_f32(h));
    }
    *(int4*)(P0 + base)        = *(const int4*)hi;
    *(int4*)(P0 + base + 2048) = *(const int4*)lo;
    if (DUAL) {
#pragma unroll
        for (int j = 0; j < 8; ++j) {
            float rv = fmaxf(v[j], 0.f);
            unsigned short h = bf16_rne(rv);
            hi[j] = (short)h;
            lo[j] = (short)bf16_rne(rv - bf16_to_f32(h));
        }
        *(int4*)(P1 + base)        = *(const int4*)hi;
        *(int4*)(P1 + base + 2048) = *(const int4*)lo;
    }
}

// ---------------- 1-wave 64x64 MFMA GEMM, glds double-buffer, counted vmcnt ----------------
// EPI 0: C = f32 (+bias), EPI 1: C packed bf16 hi/lo tile layout (+bias, relu)

template<int EPI>
__global__ __launch_bounds__(64, 2) void mfma_gemm64_kernel(
    const short* __restrict__ Apk, const short* __restrict__ Wpk,
    const float* __restrict__ bias,
    float* __restrict__ Cf, short* __restrict__ Cpk, int M)
{
    __shared__ short As[2][4096];
    __shared__ short Bs[2][4096];

    // XCD-chunked swizzle: each XCD owns ~20 consecutive rowblks x all 8 colblks
    const int bid = blockIdx.x;            // 0..1255 (=8*157)
    const int lin = (bid & 7) * RBLKS + (bid >> 3);
    const int rowblk = lin >> 3;
    const int colblk = lin & 7;

    const int lane = threadIdx.x;
    const int l15 = lane & 15;
    const int kg  = lane >> 4;
    const int kso = ((kg ^ ((l15 >> 1) & 3)) << 3);   // swizzled k-offset (lane-const)

    const short* Abase = Apk + (size_t)rowblk * 16 * 4096;
    const short* Bbase = Wpk + (size_t)colblk * 16 * 4096;

    f32x4 acc[4][4];
#pragma unroll
    for (int i = 0; i < 4; ++i)
#pragma unroll
        for (int j = 0; j < 4; ++j) acc[i][j] = (f32x4){0.f, 0.f, 0.f, 0.f};

    auto stage = [&](int buf, int kt) {
        const char* as = (const char*)(Abase + (size_t)kt * 4096);
        const char* bs = (const char*)(Bbase + (size_t)kt * 4096);
        char* ad = (char*)&As[buf][0];
        char* bd = (char*)&Bs[buf][0];
#pragma unroll
        for (int ii = 0; ii < 8; ++ii) {
            gld_lds16(as + ii * 1024 + lane * 16, ad + ii * 1024);
            gld_lds16(bs + ii * 1024 + lane * 16, bd + ii * 1024);
        }
    };

    stage(0, 0);

#pragma unroll
    for (int kt = 0; kt < 16; ++kt) {
        const int buf = kt & 1;
        if (kt < 15) {
            stage(buf ^ 1, kt + 1);
            asm volatile("s_waitcnt vmcnt(16)" ::: "memory");
        } else {
            asm volatile("s_waitcnt vmcnt(0)" ::: "memory");
        }
        __builtin_amdgcn_sched_barrier(0);

        bf16x8 af[4][2], bf[4][2];
#pragma unroll
        for (int m = 0; m < 4; ++m) {
            int ro = (m * 16 + l15) * 32 + kso;
            af[m][0] = *(const bf16x8*)&As[buf][ro];
            af[m][1] = *(const bf16x8*)&As[buf][2048 + ro];
        }
#pragma unroll
        for (int n = 0; n < 4; ++n) {
            int co = (n * 16 + l15) * 32 + kso;
            bf[n][0] = *(const bf16x8*)&Bs[buf][co];
            bf[n][1] = *(const bf16x8*)&Bs[buf][2048 + co];
        }
#pragma unroll
        for (int m = 0; m < 4; ++m)
#pragma unroll
            for (int n = 0; n < 4; ++n) {
                acc[m][n] = __builtin_amdgcn_mfma_f32_16x16x32_bf16(af[m][0], bf[n][0], acc[m][n], 0, 0, 0);
                acc[m][n] = __builtin_amdgcn_mfma_f32_16x16x32_bf16(af[m][0], bf[n][1], acc[m][n], 0, 0, 0);
                acc[m][n] = __builtin_amdgcn_mfma_f32_16x16x32_bf16(af[m][1], bf[n][0], acc[m][n], 0, 0, 0);
            }
    }

    if (EPI == 0) {
#pragma unroll
        for (int n = 0; n < 4; ++n) {
            int c = n * 16 + l15;
            float bv = bias[colblk * 64 + c];
#pragma unroll
            for (int m = 0; m < 4; ++m) {
                int r0 = rowblk * 64 + m * 16 + kg * 4;
#pragma unroll
                for (int j = 0; j < 4; ++j) {
                    int row = r0 + j;
                    if (row < M)
                        Cf[(size_t)row * 512 + colblk * 64 + c] = acc[m][n][j] + bv;
                }
            }
        }
    } else {
        // write relu(acc+bias) directly as packed hi/lo tiles (A-layout for next GEMM)
#pragma unroll
        for (int n = 0; n < 4; ++n) {
            int c   = n * 16 + l15;          // 0..63
            int k_g = colblk * 64 + c;       // global k of next GEMM
            int kt_n = k_g >> 5, kk = k_g & 31, kgn = kk >> 3, kj = kk & 7;
            float bv = bias[k_g];
#pragma unroll
            for (int m = 0; m < 4; ++m) {
#pragma unroll
                for (int j = 0; j < 4; ++j) {
                    int rl  = m * 16 + kg * 4 + j;        // row within tile
                    int row = rowblk * 64 + rl;
                    float v = (row < M) ? fmaxf(acc[m][n][j] + bv, 0.f) : 0.f;
                    unsigned short h = bf16_rne(v);
                    unsigned short l = bf16_rne(v - bf16_to_f32(h));
                    size_t dst = (size_t)(rowblk * 16 + kt_n) * 4096 + rl * 32
                               + ((kgn ^ ((rl >> 1) & 3)) << 3) + kj;
                    Cpk[dst]        = (short)h;
                    Cpk[dst + 2048] = (short)l;
                }
            }
        }
    }
}

// ---------------- aggregation (unchanged, verified) ----------------

__global__ __launch_bounds__(256) void aggregate_kernel(const float* __restrict__ H,
                                                        const float* __restrict__ dis,
                                                        const int* __restrict__ row_off,
                                                        const int* __restrict__ csr_src,
                                                        const float* __restrict__ csr_norm,
                                                        float* __restrict__ out) {
    const int node = blockIdx.x;
    const int f = threadIdx.x;
    const int start = row_off[node];
    const int end   = row_off[node + 1];
    const float dn = dis[node];
    const float sw = dn * dn;

    const float* hn = H + (size_t)node * DIM;
    float a0 = hn[f] * sw;
    float a1 = hn[f + 256] * sw;

    for (int e = start; e < end; ++e) {
        int s   = csr_src[e];
        float w = csr_norm[e];
        const float* hs = H + (size_t)s * DIM;
        a0 += hs[f] * w;
        a1 += hs[f + 256] * w;
    }
    out[(size_t)node * DIM + f]       = a0;
    out[(size_t)node * DIM + 256 + f] = a1;
}

// ---------------- launch ----------------

extern "C" void kernel_launch(void* const* d_in, const int* in_sizes, int n_in,
                              void* d_out, int out_size, void* d_ws, size_t ws_size,
                              hipStream_t stream) {
    const float* x   = (const float*)d_in[0];
    const int*   ei  = (const int*)d_in[1];
    const float* W1  = (const float*)d_in[2];
    const float* b1  = (const float*)d_in[3];
    const float* W2  = (const float*)d_in[4];
    const float* b2  = (const float*)d_in[5];
    const float* Wp1 = (const float*)d_in[6];
    const float* bp1 = (const float*)d_in[7];
    const float* Wp2 = (const float*)d_in[8];
    const float* bp2 = (const float*)d_in[9];

    float* out  = (float*)d_out;
    float* z    = out + (size_t)N_NODES * DIM;
    float* proj = z   + (size_t)N_NODES * DIM;

    char* ws = (char*)d_ws;
    size_t off = 0;
    auto walloc = [&](size_t bytes) -> void* {
        void* p = ws + off;
        off = (off + bytes + 255) & ~(size_t)255;
        return p;
    };
    const size_t PK_SHORTS = (size_t)RBLKS * 16 * 4096;   // 10.29M shorts = 20.58 MB
    float* H    = (float*)walloc((size_t)N_NODES * DIM * sizeof(float));
    short* APK0 = (short*)walloc(PK_SHORTS * sizeof(short));   // x-pack, later P1-pack
    short* ZPKp = (short*)walloc(PK_SHORTS * sizeof(short));   // z plain
    short* ZPKr = (short*)walloc(PK_SHORTS * sizeof(short));   // relu(z)
    short* WT1  = (short*)walloc((size_t)8 * 16 * 4096 * sizeof(short));
    short* WT2  = (short*)walloc((size_t)8 * 16 * 4096 * sizeof(short));
    short* WTp1 = (short*)walloc((size_t)8 * 16 * 4096 * sizeof(short));
    short* WTp2 = (short*)walloc((size_t)8 * 16 * 4096 * sizeof(short));
    int*   deg      = (int*)  walloc(N_NODES * sizeof(int));
    int*   cursor   = (int*)  walloc(N_NODES * sizeof(int));
    int*   row_off  = (int*)  walloc((N_NODES + 1) * sizeof(int));
    float* dis      = (float*)walloc(N_NODES * sizeof(float));
    int*   csr_src  = (int*)  walloc(N_EDGES * sizeof(int));
    float* csr_norm = (float*)walloc(N_EDGES * sizeof(float));

    const dim3 blk(256);
    const dim3 gN((N_NODES + 255) / 256);
    const dim3 gE((N_EDGES + 255) / 256);
    const dim3 pk_grid(16, RBLKS);
    const dim3 gemm_grid(8 * RBLKS);
    const dim3 wave(64);

    pack_weight_kernel<<<128, blk, 0, stream>>>(W1,  WT1);
    pack_weight_kernel<<<128, blk, 0, stream>>>(W2,  WT2);
    pack_weight_kernel<<<128, blk, 0, stream>>>(Wp1, WTp1);
    pack_weight_kernel<<<128, blk, 0, stream>>>(Wp2, WTp2);
    pack_a_kernel<false><<<pk_grid, blk, 0, stream>>>(x, APK0, nullptr, N_NODES);

    zero_int_kernel<<<gN, blk, 0, stream>>>(deg, N_NODES);
    zero_int_kernel<<<gN, blk, 0, stream>>>(cursor, N_NODES);
    count_deg_kernel<<<gE, blk, 0, stream>>>(ei, deg, N_EDGES);
    dis_kernel<<<gN, blk, 0, stream>>>(deg, dis, N_NODES);
    scan_kernel<<<1, 1024, 0, stream>>>(deg, row_off, N_NODES);
    scatter_kernel<<<gE, blk, 0, stream>>>(ei, dis, row_off, cursor, csr_src, csr_norm, N_EDGES);

    // z = aggregate(x @ W1 + b1)
    mfma_gemm64_kernel<0><<<gemm_grid, wave, 0, stream>>>(APK0, WT1, b1, H, nullptr, N_NODES);
    aggregate_kernel<<<N_NODES, blk, 0, stream>>>(H, dis, row_off, csr_src, csr_norm, z);

    // pack z (plain + relu)
    pack_a_kernel<true><<<pk_grid, blk, 0, stream>>>(z, ZPKp, ZPKr, N_NODES);

    // out = aggregate(relu(z) @ W2 + b2)
    mfma_gemm64_kernel<0><<<gemm_grid, wave, 0, stream>>>(ZPKr, WT2, b2, H, nullptr, N_NODES);
    aggregate_kernel<<<N_NODES, blk, 0, stream>>>(H, dis, row_off, csr_src, csr_norm, out);

    // P1 = relu(z @ Wp1 + bp1), written packed; proj = P1 @ Wp2 + bp2
    mfma_gemm64_kernel<1><<<gemm_grid, wave, 0, stream>>>(ZPKp, WTp1, bp1, nullptr, APK0, N_NODES);
    mfma_gemm64_kernel<0><<<gemm_grid, wave, 0, stream>>>(APK0, WTp2, bp2, proj, nullptr, N_NODES);
}